// Round 4
// baseline (330.360 us; speedup 1.0000x reference)
//
#include <hip/hip_runtime.h>
#include <hip/hip_bf16.h>

// R4: k_esynd rewritten as MFMA GEMM. Old k_esynd: 65us, 0.5 waves/SIMD,
// VALUBusy 2% -- serialized load->shfl->fma chain, ~448 exposed L2 latencies.
// Algebra: h = (P@cu)/rs @ W^T + b == (P @ (cu@W^T))/rs + b. New k_cuw
// precomputes cuWT=cu@W^T (bf16 hi/lo, aliases dead 'part'); k_esynd is a
// 64x64-tile MFMA GEMM (k_aggp fragment layout), rowsum via ones-column MFMA,
// BN partials via shfl_xor reduction. presc 0/1 is exact in bf16.

#define NN    1195
#define NUSER 805
#define NITEM 390
#define DD    64
#define BB    2048
#define NPAD  1216          // 19*64, padded node/k count
#define E_TOT 1000000
#define E_SUB 500000
#define MT    19            // m-tiles per graph
#define KT    8             // K-split factor
#define CHUNK 3             // ceil(19/8) k-subtiles per block
#define LSTR  72            // LDS row stride in bf16 elems
#define OUT2STRIDE (NN*DD)
#define CPG    299          // comb blocks per graph = ceil(1195*64/256)
#define P8W    152          // u32 words per histogram row (1216 u4 cells)
#define ROWS   96           // histogram rows per block (57KB LDS)
#define RB     13           // ceil(NN/ROWS)
#define FNT    13           // k_final col tiles = ceil(805/64)
#define KPAD   448          // esynd padded K (7*64)
#define ENT    7            // esynd k-steps

typedef unsigned int uint;
typedef unsigned short u16;
typedef unsigned char u8;
typedef __attribute__((ext_vector_type(8))) short short8;
typedef __attribute__((ext_vector_type(4))) float f32x4;

__device__ __forceinline__ float wsum(float v) {
#pragma unroll
    for (int m = 32; m > 0; m >>= 1) v += __shfl_xor(v, m, 64);
    return v;
}
__device__ __forceinline__ u16 f2b(float f) {           // fp32 -> bf16 RNE bits
    uint u = __float_as_uint(f);
    return (u16)((u + 0x7FFFu + ((u >> 16) & 1u)) >> 16);
}
__device__ __forceinline__ float b2f16(u16 b) { return __uint_as_float(((uint)b) << 16); }

// ---- converted-input layout (floats, relative to OFF_CVT) ----
#define CVT_EMB   0
#define CVT_W1    76480
#define CVT_B1    80576
#define CVT_W2    80640
#define CVT_B2    84736
#define CVT_MLPW  84800
#define CVT_MLPB  88896
#define CVT_GAMMA 88960
#define CVT_BETA  89024
#define CVT_TOTAL 89088

// ---------------- workspace layout (floats) ----------------
constexpr size_t alignUp64(size_t x) { return (x + 63) & ~size_t(63); }
constexpr size_t OFF_BNS  = 0;                                        // [128]
constexpr size_t OFF_CNSS = 128;                                      // [256]
constexpr size_t MEMSET_FLOATS = 384;                                 // zeroed region
constexpr size_t OFF_FLAG = 384;                                      // [16]
constexpr size_t OFF_CVT  = 448;                                      // [CVT_TOTAL]
constexpr size_t OFF_ABF  = alignUp64(OFF_CVT + CVT_TOTAL);           // bf16 A 3*NN*NPAD u16
constexpr size_t OFF_RC   = alignUp64(OFF_ABF + (3ull * NN * NPAD) / 2);
constexpr size_t OFF_POOL = alignUp64(OFF_RC + 3ull * NPAD);
constexpr size_t OFF_PART = OFF_POOL;                                 // fp32 partials KT*3*NPAD*64
constexpr size_t OFF_H1   = alignUp64(OFF_PART + (size_t)KT * 3 * NPAD * 64);
constexpr size_t OFF_H2   = alignUp64(OFF_H1 + 64ull * NPAD);
constexpr size_t OFF_OUT2 = alignUp64(OFF_H2 + 3ull * 64 * NPAD);
constexpr size_t OFF_CU   = alignUp64(OFF_OUT2 + 3ull * NN * DD);     // [448*64]
constexpr size_t OFF_CI   = alignUp64(OFF_CU + 448ull * DD);
constexpr size_t OFF_H    = alignUp64(OFF_CI + (size_t)NUSER * DD);
constexpr size_t POOL_END = alignUp64(OFF_H + (size_t)BB * DD);
// cuWT hi/lo planes alias the (dead-by-then) part buffer at OFF_PART.

// ---------------- kernels ----------------

// convert small float inputs to fp32, detect dtype, accumulate view-0 user col-sumsq
__global__ __launch_bounds__(256) void k_cvt_all(const void* presc,
        const void* p1, const void* p2, const void* p3, const void* p4,
        const void* p5, const void* p6, const void* p7, const void* p8, const void* p9,
        float* __restrict__ dst, float* __restrict__ cnss, int* __restrict__ flag) {
    int isbf = (((const u16*)presc)[0] == 0x3F80u) ? 1 : 0;   // presc[0][0]==1.0 always
    int t = threadIdx.x;
    int i = blockIdx.x * 256 + t;
    if (i == 0) *flag = isbf;
    const void* s2; int o2;
    if      (i < CVT_W1)    { s2 = p1; o2 = i; }
    else if (i < CVT_B1)    { s2 = p2; o2 = i - CVT_W1; }
    else if (i < CVT_W2)    { s2 = p3; o2 = i - CVT_B1; }
    else if (i < CVT_B2)    { s2 = p4; o2 = i - CVT_W2; }
    else if (i < CVT_MLPW)  { s2 = p5; o2 = i - CVT_B2; }
    else if (i < CVT_MLPB)  { s2 = p6; o2 = i - CVT_MLPW; }
    else if (i < CVT_GAMMA) { s2 = p7; o2 = i - CVT_MLPB; }
    else if (i < CVT_BETA)  { s2 = p8; o2 = i - CVT_GAMMA; }
    else                    { s2 = p9; o2 = i - CVT_BETA; }
    float v = isbf ? __bfloat162float(((const __hip_bfloat16*)s2)[o2])
                   : ((const float*)s2)[o2];
    dst[i] = v;
    float x2 = (i < NUSER * 64) ? v * v : 0.0f;
    __shared__ float sd[256];
    sd[t] = x2;
    __syncthreads();
    if (t < 64 && blockIdx.x * 256 < NUSER * 64) {
        float s = sd[t] + sd[t + 64] + sd[t + 128] + sd[t + 192];
        if (s != 0.0f) atomicAdd(&cnss[t], s);
    }
}

// LDS-bucketed u4 partial histograms.
__global__ __launch_bounds__(512) void k_histp(const int* __restrict__ tg,
        const int* __restrict__ s1, const int* __restrict__ s2,
        uint* __restrict__ P8, int S) {
    __shared__ __align__(16) uint lds[ROWS * P8W];
    int b = blockIdx.x;
    int p = b % S;
    int rg = b / S;
    int r = rg % RB;
    int g = rg / RB;
    int r0 = r * ROWS;
    int t = threadIdx.x;

    {
        uint4* l4 = (uint4*)lds;
        for (int i = t; i < (ROWS * P8W) >> 2; i += 512) l4[i] = (uint4){0u, 0u, 0u, 0u};
    }
    __syncthreads();

    const int* eg = (g == 0) ? tg : (g == 1 ? s1 : s2);
    int Eg = (g == 0) ? E_TOT : E_SUB;
    int e0 = (int)(((long)p * Eg / S) & ~3L);
    int e1 = (p == S - 1) ? Eg : (int)(((long)(p + 1) * Eg / S) & ~3L);
    const int* srcp = eg;
    const int* dstp = eg + Eg;
    for (int i = e0 + t * 4; i < e1; i += 512 * 4) {
        int4 d4 = *(const int4*)(dstp + i);
        int4 s4 = *(const int4*)(srcp + i);
        int rw;
        rw = d4.x - r0; if ((unsigned)rw < ROWS) atomicAdd(&lds[rw * P8W + (s4.x >> 3)], 1u << ((s4.x & 7) * 4));
        rw = d4.y - r0; if ((unsigned)rw < ROWS) atomicAdd(&lds[rw * P8W + (s4.y >> 3)], 1u << ((s4.y & 7) * 4));
        rw = d4.z - r0; if ((unsigned)rw < ROWS) atomicAdd(&lds[rw * P8W + (s4.z >> 3)], 1u << ((s4.z & 7) * 4));
        rw = d4.w - r0; if ((unsigned)rw < ROWS) atomicAdd(&lds[rw * P8W + (s4.w >> 3)], 1u << ((s4.w & 7) * 4));
    }
    __syncthreads();

    int rmax = ROWS; if (r0 + rmax > NN) rmax = NN - r0;
    uint* out = P8 + ((size_t)p * 3 + g) * NN * P8W + (size_t)r0 * P8W;
    int n4 = (rmax * P8W) >> 2;
    const uint4* l4 = (const uint4*)lds;
    uint4* o4 = (uint4*)out;
    for (int i = t; i < n4; i += 512) o4[i] = l4[i];
}

// merge S u4 partial copies -> bf16 A row (pad cols zero) + reciprocal in-degree
__global__ __launch_bounds__(256) void k_abfrc(const uint* __restrict__ P8, int S,
        u16* __restrict__ Abf, float* __restrict__ rcnt) {
    int row = blockIdx.x;            // 0..3*NN-1
    int g = row / NN, m = row % NN;
    int t = threadIdx.x, w = t >> 6;
    float partial = 0.0f;
    if (t < P8W) {
        uint cnt[8] = {0, 0, 0, 0, 0, 0, 0, 0};
        for (int p = 0; p < S; ++p) {
            uint v = P8[(((size_t)p * 3 + g) * NN + m) * P8W + t];
#pragma unroll
            for (int k = 0; k < 8; ++k) cnt[k] += (v >> (4 * k)) & 15u;
        }
        uint4 o;
        o.x = (uint)f2b((float)cnt[0]) | ((uint)f2b((float)cnt[1]) << 16);
        o.y = (uint)f2b((float)cnt[2]) | ((uint)f2b((float)cnt[3]) << 16);
        o.z = (uint)f2b((float)cnt[4]) | ((uint)f2b((float)cnt[5]) << 16);
        o.w = (uint)f2b((float)cnt[6]) | ((uint)f2b((float)cnt[7]) << 16);
        *(uint4*)(Abf + (size_t)row * NPAD + t * 8) = o;
#pragma unroll
        for (int k = 0; k < 8; ++k) partial += (float)cnt[k];
    }
    partial = wsum(partial);
    __shared__ float ws4[4];
    if ((t & 63) == 0) ws4[w] = partial;
    __syncthreads();
    if (t == 0)
        rcnt[g * NPAD + m] = 1.0f / fmaxf(ws4[0] + ws4[1] + ws4[2] + ws4[3], 1.0f);
}

// Linear transform -> transposed bf16 hi/lo planes [g][64 dims][NPAD nodes].
__global__ __launch_bounds__(256) void k_xf(const float* __restrict__ x, size_t xgstride,
        const float* __restrict__ part, const float* __restrict__ rcnt, int fromPart,
        const float* __restrict__ W, const float* __restrict__ bias,
        u16* __restrict__ Hhi, u16* __restrict__ Hlo, size_t hgstride) {
    int b = blockIdx.x;
    int g = b / MT, nt = b % MT;
    int t = threadIdx.x, w = t >> 6, l = t & 63;
    int n0 = nt * 64;
    __shared__ float Ws[64 * 65];
    __shared__ float bs[64];
    __shared__ float Ts[64 * 68];
    for (int i = t; i < 4096; i += 256) Ws[(i >> 6) * 65 + (i & 63)] = W[i];
    if (t < 64) bs[t] = bias[t];
    float xr[16];
#pragma unroll
    for (int i = 0; i < 16; ++i) {
        int node = n0 + w * 16 + i;
        float v = 0.0f;
        if (node < NN) {
            if (fromPart) {
                float s = 0.0f;
#pragma unroll
                for (int k = 0; k < KT; ++k)
                    s += part[(((size_t)k * 3 + g) * NPAD + node) * 64 + l];
                v = tanhf(s * rcnt[g * NPAD + node]);
            } else {
                v = x[xgstride * g + (size_t)node * 64 + l];
            }
        }
        xr[i] = v;
    }
    __syncthreads();
#pragma unroll
    for (int i = 0; i < 16; ++i) {
        int node = n0 + w * 16 + i;
        float acc = 0.0f;
        if (node < NN) {
            acc = bs[l];
#pragma unroll
            for (int k = 0; k < 64; ++k)
                acc = fmaf(__shfl(xr[i], k, 64), Ws[l * 65 + k], acc);
        }
        Ts[l * 68 + w * 16 + i] = acc;
    }
    __syncthreads();
    int d = t >> 2, seg = t & 3;
    u16 hb[16], lb[16];
#pragma unroll
    for (int j = 0; j < 16; ++j) {
        float v = Ts[d * 68 + seg * 16 + j];
        u16 h = f2b(v);
        hb[j] = h;
        lb[j] = f2b(v - b2f16(h));
    }
    size_t base = hgstride * g + (size_t)d * NPAD + n0 + seg * 16;
#pragma unroll
    for (int j = 0; j < 4; ++j) {
        uint2 ph, pl;
        ph.x = (uint)hb[j*4]   | ((uint)hb[j*4+1] << 16);
        ph.y = (uint)hb[j*4+2] | ((uint)hb[j*4+3] << 16);
        pl.x = (uint)lb[j*4]   | ((uint)lb[j*4+1] << 16);
        pl.y = (uint)lb[j*4+2] | ((uint)lb[j*4+3] << 16);
        *(uint2*)(Hhi + base + j*4) = ph;
        *(uint2*)(Hlo + base + j*4) = pl;
    }
}

// MFMA aggregation with split-bf16 B; K-split partials
__global__ __launch_bounds__(256) void k_aggp(const u16* __restrict__ Abf,
        const u16* __restrict__ Hhi, const u16* __restrict__ Hlo, size_t hstride,
        float* __restrict__ part) {
    int b = blockIdx.x;
    int kt = b & 7;
    int mt = (b >> 3) % MT;
    int g  = (b >> 3) / MT;
    int t = threadIdx.x, w = t >> 6, l = t & 63;
    __shared__ u16 As[64 * LSTR], Bh[64 * LSTR], Bl[64 * LSTR];
    f32x4 acc[4];
#pragma unroll
    for (int p = 0; p < 4; ++p) acc[p] = (f32x4){0.f, 0.f, 0.f, 0.f};
    int m0 = mt * 64;
    const u16* Ag = Abf + (size_t)g * NN * NPAD;
    const u16* Hg = Hhi + hstride * g;
    const u16* Lg = Hlo + hstride * g;
    int st0 = kt * CHUNK;
    int st1 = st0 + CHUNK; if (st1 > MT) st1 = MT;
    int rr = t >> 4, c4 = (t & 15) * 4;
    for (int st = st0; st < st1; ++st) {
        int s0 = st * 64;
        __syncthreads();
#pragma unroll
        for (int pass = 0; pass < 4; ++pass) {
            int r = pass * 16 + rr;
            uint2 av = {0u, 0u};
            if (m0 + r < NN) av = *(const uint2*)(Ag + (size_t)(m0 + r) * NPAD + s0 + c4);
            *(uint2*)(As + r * LSTR + c4) = av;
            *(uint2*)(Bh + r * LSTR + c4) = *(const uint2*)(Hg + (size_t)r * NPAD + s0 + c4);
            *(uint2*)(Bl + r * LSTR + c4) = *(const uint2*)(Lg + (size_t)r * NPAD + s0 + c4);
        }
        __syncthreads();
        int mrow = w * 16 + (l & 15);
        int q8 = (l >> 4) * 8;
#pragma unroll
        for (int ks = 0; ks < 2; ++ks) {
            short8 a = *(const short8*)(As + mrow * LSTR + ks * 32 + q8);
#pragma unroll
            for (int p = 0; p < 4; ++p) {
                int nrow = p * 16 + (l & 15);
                short8 bh = *(const short8*)(Bh + nrow * LSTR + ks * 32 + q8);
                short8 bl = *(const short8*)(Bl + nrow * LSTR + ks * 32 + q8);
                acc[p] = __builtin_amdgcn_mfma_f32_16x16x32_bf16(a, bh, acc[p], 0, 0, 0);
                acc[p] = __builtin_amdgcn_mfma_f32_16x16x32_bf16(a, bl, acc[p], 0, 0, 0);
            }
        }
    }
    int q = l >> 4;
#pragma unroll
    for (int p = 0; p < 4; ++p) {
        int n = p * 16 + (l & 15);
#pragma unroll
        for (int r = 0; r < 4; ++r) {
            int m = m0 + w * 16 + q * 4 + r;
            if (m < NN)
                part[(((size_t)kt * 3 + g) * NPAD + m) * 64 + n] = acc[p][r];
        }
    }
}

// layer-2 combine + views-1..3 user column sumsq accumulation
__global__ __launch_bounds__(256) void k_comb(const float* __restrict__ part,
        const float* __restrict__ rcnt, float* __restrict__ out, float* __restrict__ cnss) {
    int g = blockIdx.x / CPG, bi = blockIdx.x % CPG;
    int t = threadIdx.x;
    int idx = bi * 256 + t;                 // within graph
    int m = idx >> 6, n = idx & 63;
    bool valid = idx < NN * 64;
    float v = 0.0f;
    if (valid) {
        float s = 0.0f;
#pragma unroll
        for (int k = 0; k < KT; ++k)
            s += part[(((size_t)k * 3 + g) * NPAD + m) * 64 + n];
        v = tanhf(s * rcnt[g * NPAD + m]);
        out[(size_t)g * NN * 64 + idx] = v;
    }
    float x2 = (valid && m < NUSER) ? v * v : 0.0f;
    __shared__ float sd[256];
    sd[t] = x2;
    __syncthreads();
    if (t < 64) {
        float s = sd[t] + sd[t + 64] + sd[t + 128] + sd[t + 192];
        if (s != 0.0f) atomicAdd(&cnss[(g + 1) * 64 + t], s);
    }
}

// cu (item rows, 4-view row-norm fusion) + ci (user rows, 4-view col-norm fusion)
__global__ void k_cuci(const float* __restrict__ embf, const float* __restrict__ out2,
                       const float* __restrict__ cnss, float* __restrict__ cu,
                       float* __restrict__ ci) {
    int b = blockIdx.x, l = threadIdx.x;
    if (b < 448) {
        if (b >= NITEM) { cu[(size_t)b * DD + l] = 0.0f; return; }
        int node = NUSER + b;
        const float* v0 = embf + (size_t)node * DD;
        const float* v1 = out2 + (size_t)node * DD;
        const float* v2 = out2 + OUT2STRIDE + (size_t)node * DD;
        const float* v3 = out2 + 2ull * OUT2STRIDE + (size_t)node * DD;
        float total = 0.0f;
        { float x = v0[l]; float ss = wsum(x * x); total += x / sqrtf(ss); }
        { float x = v1[l]; float ss = wsum(x * x); total += x / sqrtf(ss); }
        { float x = v2[l]; float ss = wsum(x * x); total += x / sqrtf(ss); }
        { float x = v3[l]; float ss = wsum(x * x); total += x / sqrtf(ss); }
        cu[(size_t)b * DD + l] = 0.25f * total;
    } else {
        int u = b - 448;
        size_t i = (size_t)u * DD + l;
        float s = embf[i] / sqrtf(cnss[l])
                + out2[i] / sqrtf(cnss[64 + l])
                + out2[OUT2STRIDE + i] / sqrtf(cnss[128 + l])
                + out2[2ull * OUT2STRIDE + i] / sqrtf(cnss[192 + l]);
        ci[i] = 0.25f * s;
    }
}

// cuWT[d][k] = sum_c mlpW[d][c]*cu[k][c], split bf16 hi/lo, [64][448].
// cu rows >= NITEM are zero, so k in [390,448) auto-zeroes.
__global__ __launch_bounds__(256) void k_cuw(const float* __restrict__ cu,
        const float* __restrict__ mlpW, u16* __restrict__ cwh, u16* __restrict__ cwl) {
    int k0 = blockIdx.x * 64;
    int t = threadIdx.x, w = t >> 6, l = t & 63;
    __shared__ float Wm[64 * 65];
    __shared__ float Cs[64 * 65];
    for (int i = t; i < 4096; i += 256) {
        Wm[(i >> 6) * 65 + (i & 63)] = mlpW[i];
        Cs[(i >> 6) * 65 + (i & 63)] = cu[(size_t)(k0 + (i >> 6)) * 64 + (i & 63)];
    }
    __syncthreads();
#pragma unroll
    for (int j = 0; j < 16; ++j) {
        int i = w * 16 + j;
        float acc = 0.0f;
#pragma unroll
        for (int c = 0; c < 64; ++c) acc = fmaf(Wm[l * 65 + c], Cs[i * 65 + c], acc);
        u16 hb = f2b(acc);
        cwh[l * KPAD + k0 + i] = hb;
        cwl[l * KPAD + k0 + i] = f2b(acc - b2f16(hb));
    }
}

// h_pre = (presc @ cuWT^T)/rowsum + bias via MFMA; rowsum from ones-column MFMA;
// + BN partial sums. Fragment layout identical to k_aggp.
__global__ __launch_bounds__(256) void k_esynd(const void* __restrict__ presc,
        const u16* __restrict__ cwh, const u16* __restrict__ cwl,
        const float* __restrict__ mlpB, const int* __restrict__ flag,
        float* __restrict__ hpre, float* __restrict__ bnsum) {
    int m0 = blockIdx.x * 64;
    int t = threadIdx.x, w = t >> 6, l = t & 63;
    int isbf = *flag;
    const u16* pB = (const u16*)presc;
    const float* pF = (const float*)presc;
    __shared__ u16 As[64 * LSTR], Bh[64 * LSTR], Bl[64 * LSTR];
    __shared__ u16 Ones[16 * LSTR];
    __shared__ float bs[64];
    __shared__ float r1[4][64], r2[4][64];
    for (int i = t; i < 16 * LSTR; i += 256) Ones[i] = (i < 64) ? 0x3F80u : 0u;
    if (t < 64) bs[t] = mlpB[t];

    f32x4 acc[4], acc1;
#pragma unroll
    for (int p = 0; p < 4; ++p) acc[p] = (f32x4){0.f, 0.f, 0.f, 0.f};
    acc1 = (f32x4){0.f, 0.f, 0.f, 0.f};

    int rr = t >> 4, c4 = (t & 15) * 4;
    for (int st = 0; st < ENT; ++st) {
        int s0 = st * 64;
        __syncthreads();
#pragma unroll
        for (int pass = 0; pass < 4; ++pass) {
            int r = pass * 16 + rr;
            int m = m0 + r;
            int kb = s0 + c4;
            u16 a4[4];
            if (kb + 3 < NITEM) {
                if (isbf) {
                    const uint* p32 = (const uint*)pB + (((size_t)m * NITEM + kb) >> 1);
                    uint u0 = p32[0], u1 = p32[1];
                    a4[0] = (u16)u0; a4[1] = (u16)(u0 >> 16);
                    a4[2] = (u16)u1; a4[3] = (u16)(u1 >> 16);
                } else {
                    const float2* pf2 = (const float2*)(pF + (size_t)m * NITEM + kb);
                    float2 f0 = pf2[0], f1 = pf2[1];
                    a4[0] = f2b(f0.x); a4[1] = f2b(f0.y);
                    a4[2] = f2b(f1.x); a4[3] = f2b(f1.y);
                }
            } else {
#pragma unroll
                for (int j = 0; j < 4; ++j) {
                    int k = kb + j;
                    a4[j] = (k < NITEM)
                          ? (isbf ? pB[(size_t)m * NITEM + k] : f2b(pF[(size_t)m * NITEM + k]))
                          : (u16)0;
                }
            }
            uint2 o;
            o.x = (uint)a4[0] | ((uint)a4[1] << 16);
            o.y = (uint)a4[2] | ((uint)a4[3] << 16);
            *(uint2*)(As + r * LSTR + c4) = o;
            *(uint2*)(Bh + r * LSTR + c4) = *(const uint2*)(cwh + (size_t)r * KPAD + s0 + c4);
            *(uint2*)(Bl + r * LSTR + c4) = *(const uint2*)(cwl + (size_t)r * KPAD + s0 + c4);
        }
        __syncthreads();
        int mrow = w * 16 + (l & 15);
        int q8 = (l >> 4) * 8;
#pragma unroll
        for (int ks = 0; ks < 2; ++ks) {
            short8 a = *(const short8*)(As + mrow * LSTR + ks * 32 + q8);
            short8 on = *(const short8*)(Ones + (l & 15) * LSTR + ks * 32 + q8);
            acc1 = __builtin_amdgcn_mfma_f32_16x16x32_bf16(a, on, acc1, 0, 0, 0);
#pragma unroll
            for (int p = 0; p < 4; ++p) {
                int nrow = p * 16 + (l & 15);
                short8 bh = *(const short8*)(Bh + nrow * LSTR + ks * 32 + q8);
                short8 bl = *(const short8*)(Bl + nrow * LSTR + ks * 32 + q8);
                acc[p] = __builtin_amdgcn_mfma_f32_16x16x32_bf16(a, bh, acc[p], 0, 0, 0);
                acc[p] = __builtin_amdgcn_mfma_f32_16x16x32_bf16(a, bl, acc[p], 0, 0, 0);
            }
        }
    }
    // rowsum broadcast: col-0 lane of my q-group (lane l&48) holds rowsum for rows q*4+..
    float inv[4];
#pragma unroll
    for (int r = 0; r < 4; ++r)
        inv[r] = 1.0f / __shfl(acc1[r], l & 48, 64);
    int q = l >> 4;
#pragma unroll
    for (int p = 0; p < 4; ++p) {
        int col = p * 16 + (l & 15);
        float a = 0.0f, c = 0.0f;
#pragma unroll
        for (int r = 0; r < 4; ++r) {
            float hv = acc[p][r] * inv[r] + bs[col];
            hpre[(size_t)(m0 + w * 16 + q * 4 + r) * DD + col] = hv;
            a += hv; c = fmaf(hv, hv, c);
        }
        a += __shfl_xor(a, 16, 64); a += __shfl_xor(a, 32, 64);
        c += __shfl_xor(c, 16, 64); c += __shfl_xor(c, 32, 64);
        if (l < 16) { r1[w][col] = a; r2[w][col] = c; }
    }
    __syncthreads();
    if (t < 64) {
        atomicAdd(&bnsum[t],      r1[0][t] + r1[1][t] + r1[2][t] + r1[3][t]);
        atomicAdd(&bnsum[64 + t], r2[0][t] + r2[1][t] + r2[2][t] + r2[3][t]);
    }
}

// pre = relu(BN(h_pre)) @ ci^T via MFMA 64x64 tiles, bf16 hi/lo both operands.
__global__ __launch_bounds__(256) void k_final(const float* __restrict__ hpre,
        const float* __restrict__ bnsum, const float* __restrict__ gamma,
        const float* __restrict__ beta, const float* __restrict__ ci,
        void* __restrict__ out, const int* __restrict__ flag) {
    int b = blockIdx.x;
    int mt = b / FNT, nt = b % FNT;
    int m0 = mt * 64, n0 = nt * 64;
    int t = threadIdx.x, w = t >> 6, l = t & 63;
    __shared__ u16 Ah[64 * LSTR], Al[64 * LSTR], Bh[64 * LSTR], Bl[64 * LSTR];
    __shared__ float mn[64], rsg[64], bt[64];
    if (t < 64) {
        float mean = bnsum[t] * (1.0f / BB);
        float var = bnsum[64 + t] * (1.0f / BB) - mean * mean;
        mn[t] = mean;
        rsg[t] = gamma[t] / sqrtf(var + 1e-5f);
        bt[t] = beta[t];
    }
    __syncthreads();
    const float4* hp4 = (const float4*)(hpre + (size_t)m0 * 64);
    const float4* ci4 = (const float4*)ci;
#pragma unroll
    for (int k = 0; k < 4; ++k) {
        int i = t + k * 256;
        int r = i >> 4, c4 = (i & 15) * 4;
        float4 v = hp4[i];
        float vv[4] = {v.x, v.y, v.z, v.w};
        u16 hh[4], ll[4];
#pragma unroll
        for (int j = 0; j < 4; ++j) {
            int d = c4 + j;
            float x = fmaxf((vv[j] - mn[d]) * rsg[d] + bt[d], 0.0f);
            u16 hb = f2b(x);
            hh[j] = hb;
            ll[j] = f2b(x - b2f16(hb));
        }
        uint2 ph, pl;
        ph.x = (uint)hh[0] | ((uint)hh[1] << 16);
        ph.y = (uint)hh[2] | ((uint)hh[3] << 16);
        pl.x = (uint)ll[0] | ((uint)ll[1] << 16);
        pl.y = (uint)ll[2] | ((uint)ll[3] << 16);
        *(uint2*)(Ah + r * LSTR + c4) = ph;
        *(uint2*)(Al + r * LSTR + c4) = pl;
        int col = n0 + r;
        float4 cv = (col < NUSER) ? ci4[(size_t)col * 16 + (i & 15)]
                                  : (float4){0.f, 0.f, 0.f, 0.f};
        float cc[4] = {cv.x, cv.y, cv.z, cv.w};
#pragma unroll
        for (int j = 0; j < 4; ++j) {
            u16 hb = f2b(cc[j]);
            hh[j] = hb;
            ll[j] = f2b(cc[j] - b2f16(hb));
        }
        ph.x = (uint)hh[0] | ((uint)hh[1] << 16);
        ph.y = (uint)hh[2] | ((uint)hh[3] << 16);
        pl.x = (uint)ll[0] | ((uint)ll[1] << 16);
        pl.y = (uint)ll[2] | ((uint)ll[3] << 16);
        *(uint2*)(Bh + r * LSTR + c4) = ph;
        *(uint2*)(Bl + r * LSTR + c4) = pl;
    }
    __syncthreads();
    f32x4 acc[4];
#pragma unroll
    for (int p = 0; p < 4; ++p) acc[p] = (f32x4){0.f, 0.f, 0.f, 0.f};
    int mrow = w * 16 + (l & 15);
    int q8 = (l >> 4) * 8;
#pragma unroll
    for (int ks = 0; ks < 2; ++ks) {
        short8 ah = *(const short8*)(Ah + mrow * LSTR + ks * 32 + q8);
        short8 al = *(const short8*)(Al + mrow * LSTR + ks * 32 + q8);
#pragma unroll
        for (int p = 0; p < 4; ++p) {
            int nrow = p * 16 + (l & 15);
            short8 bh = *(const short8*)(Bh + nrow * LSTR + ks * 32 + q8);
            short8 bl = *(const short8*)(Bl + nrow * LSTR + ks * 32 + q8);
            acc[p] = __builtin_amdgcn_mfma_f32_16x16x32_bf16(ah, bh, acc[p], 0, 0, 0);
            acc[p] = __builtin_amdgcn_mfma_f32_16x16x32_bf16(ah, bl, acc[p], 0, 0, 0);
            acc[p] = __builtin_amdgcn_mfma_f32_16x16x32_bf16(al, bh, acc[p], 0, 0, 0);
        }
    }
    int isbf = *flag;
    int q = l >> 4;
#pragma unroll
    for (int p = 0; p < 4; ++p) {
        int col = n0 + p * 16 + (l & 15);
        if (col < NUSER) {
#pragma unroll
            for (int r = 0; r < 4; ++r) {
                int row = m0 + w * 16 + q * 4 + r;
                size_t o = (size_t)row * NUSER + col;
                if (isbf) ((__hip_bfloat16*)out)[o] = __float2bfloat16(acc[p][r]);
                else      ((float*)out)[o] = acc[p][r];
            }
        }
    }
}

extern "C" void kernel_launch(void* const* d_in, const int* in_sizes, int n_in,
                              void* d_out, int out_size, void* d_ws, size_t ws_size,
                              hipStream_t stream) {
    const void* presc = d_in[1];
    const void* emb   = d_in[2];
    const void* W1    = d_in[3];
    const void* b1    = d_in[4];
    const void* W2    = d_in[5];
    const void* b2    = d_in[6];
    const void* mlpW  = d_in[7];
    const void* mlpB  = d_in[8];
    const void* gamma = d_in[9];
    const void* beta  = d_in[10];
    const int* tg = (const int*)d_in[11];
    const int* s1 = (const int*)d_in[12];
    const int* s2 = (const int*)d_in[13];
    float* ws = (float*)d_ws;
    (void)in_sizes; (void)n_in; (void)out_size;

    float* bnsum = ws + OFF_BNS;
    float* cnss  = ws + OFF_CNSS;
    int*   flag  = (int*)(ws + OFF_FLAG);
    float* cvt   = ws + OFF_CVT;
    float* embF  = cvt + CVT_EMB;
    float* W1F   = cvt + CVT_W1;
    float* b1F   = cvt + CVT_B1;
    float* W2F   = cvt + CVT_W2;
    float* b2F   = cvt + CVT_B2;
    float* mlpWF = cvt + CVT_MLPW;
    float* mlpBF = cvt + CVT_MLPB;
    float* gamF  = cvt + CVT_GAMMA;
    float* betF  = cvt + CVT_BETA;
    u16*   Abf   = (u16*)(ws + OFF_ABF);
    float* rcnt  = ws + OFF_RC;
    uint*  P8    = (uint*)(ws + OFF_POOL);
    float* part  = ws + OFF_PART;
    u16*   H1hi  = (u16*)(ws + OFF_H1);
    u16*   H1lo  = H1hi + 64ull * NPAD;
    u16*   H2hi  = (u16*)(ws + OFF_H2);
    u16*   H2lo  = H2hi + 3ull * 64 * NPAD;
    float* out2  = ws + OFF_OUT2;
    float* cu    = ws + OFF_CU;
    float* ci    = ws + OFF_CI;
    float* hpre  = ws + OFF_H;
    // cuWT hi/lo alias the dead part buffer (part last read by k_xf L2 / k_comb)
    u16*   cwh   = (u16*)(ws + OFF_PART);
    u16*   cwl   = cwh + 64ull * KPAD;

    size_t p8per = 3ull * NN * P8W;        // floats (==u32) per partial copy
    int S = 4;
    if      (ws_size >= (OFF_POOL + 16ull * p8per) * 4) S = 16;
    else if (ws_size >= (OFF_POOL +  8ull * p8per) * 4) S = 8;

    hipMemsetAsync(ws, 0, MEMSET_FLOATS * sizeof(float), stream);   // bnsum + cnss
    k_cvt_all<<<CVT_TOTAL / 256, 256, 0, stream>>>(
        presc, emb, W1, b1, W2, b2, mlpW, mlpB, gamma, beta, cvt, cnss, flag);

    k_histp<<<3 * RB * S, 512, 0, stream>>>(tg, s1, s2, P8, S);
    k_abfrc<<<3 * NN, 256, 0, stream>>>(P8, S, Abf, rcnt);

    // layer 1
    k_xf<<<MT, 256, 0, stream>>>(embF, 0, nullptr, nullptr, 0, W1F, b1F, H1hi, H1lo, 0);
    k_aggp<<<3 * MT * KT, 256, 0, stream>>>(Abf, H1hi, H1lo, 0, part);
    // layer 2
    k_xf<<<3 * MT, 256, 0, stream>>>(nullptr, 0, part, rcnt, 1, W2F, b2F, H2hi, H2lo, 64ull * NPAD);
    k_aggp<<<3 * MT * KT, 256, 0, stream>>>(Abf, H2hi, H2lo, 64ull * NPAD, part);
    k_comb<<<3 * CPG, 256, 0, stream>>>(part, rcnt, out2, cnss);

    // view fusion
    k_cuci<<<448 + NUSER, 64, 0, stream>>>(embF, out2, cnss, cu, ci);
    k_cuw<<<ENT, 256, 0, stream>>>(cu, mlpWF, cwh, cwl);

    // pooling+MLP GEMM (+BN partials) + final GEMM
    k_esynd<<<BB / 64, 256, 0, stream>>>(presc, cwh, cwl, mlpBF, flag, hpre, bnsum);
    k_final<<<(BB / 64) * FNT, 256, 0, stream>>>(hpre, bnsum, gamF, betF, ci, d_out, flag);
}

// Round 5
// 215.891 us; speedup vs baseline: 1.5302x; 1.5302x over previous
//
#include <hip/hip_runtime.h>
#include <hip/hip_bf16.h>

// R5: kill the serial shfl-GEMM pattern. k_xf was 58us/dispatch (grid 57,
// occupancy 2.3%, VALUBusy 1.1%): per-block 1024-step dependent shfl->fma
// chain + scattered KT-partial loads. Replaced by k_xf2: MFMA tile kernel
// computing C[d][node]=W@x^T directly in transposed layout (hi/lo split both
// operands, hh+hl+lh), reused for L1, L2, and cu@W^T (ex-k_cuw). The L2
// partial-combine+tanh moves to wide k_comb1 (grid 897) writing fp32 h1agg.

#define NN    1195
#define NUSER 805
#define NITEM 390
#define DD    64
#define BB    2048
#define NPAD  1216          // 19*64, padded node/k count
#define E_TOT 1000000
#define E_SUB 500000
#define MT    19            // m-tiles per graph
#define KT    8             // K-split factor
#define CHUNK 3             // ceil(19/8) k-subtiles per block
#define LSTR  72            // LDS row stride in bf16 elems
#define OUT2STRIDE (NN*DD)
#define CPG    299          // comb blocks per graph = ceil(1195*64/256)
#define P8W    152          // u32 words per histogram row (1216 u4 cells)
#define ROWS   96           // histogram rows per block (57KB LDS)
#define RB     13           // ceil(NN/ROWS)
#define FNT    13           // k_final col tiles = ceil(805/64)
#define KPAD   448          // esynd padded K (7*64)
#define ENT    7            // esynd k-steps

typedef unsigned int uint;
typedef unsigned short u16;
typedef unsigned char u8;
typedef __attribute__((ext_vector_type(8))) short short8;
typedef __attribute__((ext_vector_type(4))) float f32x4;

__device__ __forceinline__ float wsum(float v) {
#pragma unroll
    for (int m = 32; m > 0; m >>= 1) v += __shfl_xor(v, m, 64);
    return v;
}
__device__ __forceinline__ u16 f2b(float f) {           // fp32 -> bf16 RNE bits
    uint u = __float_as_uint(f);
    return (u16)((u + 0x7FFFu + ((u >> 16) & 1u)) >> 16);
}
__device__ __forceinline__ float b2f16(u16 b) { return __uint_as_float(((uint)b) << 16); }

// ---- converted-input layout (floats, relative to OFF_CVT) ----
#define CVT_EMB   0
#define CVT_W1    76480
#define CVT_B1    80576
#define CVT_W2    80640
#define CVT_B2    84736
#define CVT_MLPW  84800
#define CVT_MLPB  88896
#define CVT_GAMMA 88960
#define CVT_BETA  89024
#define CVT_TOTAL 89088

// ---------------- workspace layout (floats) ----------------
constexpr size_t alignUp64(size_t x) { return (x + 63) & ~size_t(63); }
constexpr size_t OFF_BNS  = 0;                                        // [128]
constexpr size_t OFF_CNSS = 128;                                      // [256]
constexpr size_t MEMSET_FLOATS = 384;                                 // zeroed region
constexpr size_t OFF_FLAG = 384;                                      // [16]
constexpr size_t OFF_CVT  = 448;                                      // [CVT_TOTAL]
constexpr size_t OFF_ABF  = alignUp64(OFF_CVT + CVT_TOTAL);           // bf16 A 3*NN*NPAD u16
constexpr size_t OFF_RC   = alignUp64(OFF_ABF + (3ull * NN * NPAD) / 2);
constexpr size_t OFF_POOL = alignUp64(OFF_RC + 3ull * NPAD);
constexpr size_t OFF_PART = OFF_POOL;                                 // fp32 partials KT*3*NPAD*64
constexpr size_t OFF_H1   = alignUp64(OFF_PART + (size_t)KT * 3 * NPAD * 64);
constexpr size_t OFF_H2   = alignUp64(OFF_H1 + 64ull * NPAD);
constexpr size_t OFF_OUT2 = alignUp64(OFF_H2 + 3ull * 64 * NPAD);     // h1agg then out2
constexpr size_t OFF_CU   = alignUp64(OFF_OUT2 + 3ull * NN * DD);     // [448*64]
constexpr size_t OFF_CI   = alignUp64(OFF_CU + 448ull * DD);
constexpr size_t OFF_H    = alignUp64(OFF_CI + (size_t)NUSER * DD);
constexpr size_t POOL_END = alignUp64(OFF_H + (size_t)BB * DD);
// cuWT hi/lo planes alias the (dead-by-then) part buffer at OFF_PART.

// ---------------- kernels ----------------

// convert small float inputs to fp32, detect dtype, accumulate view-0 user col-sumsq
__global__ __launch_bounds__(256) void k_cvt_all(const void* presc,
        const void* p1, const void* p2, const void* p3, const void* p4,
        const void* p5, const void* p6, const void* p7, const void* p8, const void* p9,
        float* __restrict__ dst, float* __restrict__ cnss, int* __restrict__ flag) {
    int isbf = (((const u16*)presc)[0] == 0x3F80u) ? 1 : 0;   // presc[0][0]==1.0 always
    int t = threadIdx.x;
    int i = blockIdx.x * 256 + t;
    if (i == 0) *flag = isbf;
    const void* s2; int o2;
    if      (i < CVT_W1)    { s2 = p1; o2 = i; }
    else if (i < CVT_B1)    { s2 = p2; o2 = i - CVT_W1; }
    else if (i < CVT_W2)    { s2 = p3; o2 = i - CVT_B1; }
    else if (i < CVT_B2)    { s2 = p4; o2 = i - CVT_W2; }
    else if (i < CVT_MLPW)  { s2 = p5; o2 = i - CVT_B2; }
    else if (i < CVT_MLPB)  { s2 = p6; o2 = i - CVT_MLPW; }
    else if (i < CVT_GAMMA) { s2 = p7; o2 = i - CVT_MLPB; }
    else if (i < CVT_BETA)  { s2 = p8; o2 = i - CVT_GAMMA; }
    else                    { s2 = p9; o2 = i - CVT_BETA; }
    float v = isbf ? __bfloat162float(((const __hip_bfloat16*)s2)[o2])
                   : ((const float*)s2)[o2];
    dst[i] = v;
    float x2 = (i < NUSER * 64) ? v * v : 0.0f;
    __shared__ float sd[256];
    sd[t] = x2;
    __syncthreads();
    if (t < 64 && blockIdx.x * 256 < NUSER * 64) {
        float s = sd[t] + sd[t + 64] + sd[t + 128] + sd[t + 192];
        if (s != 0.0f) atomicAdd(&cnss[t], s);
    }
}

// LDS-bucketed u4 partial histograms.
__global__ __launch_bounds__(512) void k_histp(const int* __restrict__ tg,
        const int* __restrict__ s1, const int* __restrict__ s2,
        uint* __restrict__ P8, int S) {
    __shared__ __align__(16) uint lds[ROWS * P8W];
    int b = blockIdx.x;
    int p = b % S;
    int rg = b / S;
    int r = rg % RB;
    int g = rg / RB;
    int r0 = r * ROWS;
    int t = threadIdx.x;

    {
        uint4* l4 = (uint4*)lds;
        for (int i = t; i < (ROWS * P8W) >> 2; i += 512) l4[i] = (uint4){0u, 0u, 0u, 0u};
    }
    __syncthreads();

    const int* eg = (g == 0) ? tg : (g == 1 ? s1 : s2);
    int Eg = (g == 0) ? E_TOT : E_SUB;
    int e0 = (int)(((long)p * Eg / S) & ~3L);
    int e1 = (p == S - 1) ? Eg : (int)(((long)(p + 1) * Eg / S) & ~3L);
    const int* srcp = eg;
    const int* dstp = eg + Eg;
    for (int i = e0 + t * 4; i < e1; i += 512 * 4) {
        int4 d4 = *(const int4*)(dstp + i);
        int4 s4 = *(const int4*)(srcp + i);
        int rw;
        rw = d4.x - r0; if ((unsigned)rw < ROWS) atomicAdd(&lds[rw * P8W + (s4.x >> 3)], 1u << ((s4.x & 7) * 4));
        rw = d4.y - r0; if ((unsigned)rw < ROWS) atomicAdd(&lds[rw * P8W + (s4.y >> 3)], 1u << ((s4.y & 7) * 4));
        rw = d4.z - r0; if ((unsigned)rw < ROWS) atomicAdd(&lds[rw * P8W + (s4.z >> 3)], 1u << ((s4.z & 7) * 4));
        rw = d4.w - r0; if ((unsigned)rw < ROWS) atomicAdd(&lds[rw * P8W + (s4.w >> 3)], 1u << ((s4.w & 7) * 4));
    }
    __syncthreads();

    int rmax = ROWS; if (r0 + rmax > NN) rmax = NN - r0;
    uint* out = P8 + ((size_t)p * 3 + g) * NN * P8W + (size_t)r0 * P8W;
    int n4 = (rmax * P8W) >> 2;
    const uint4* l4 = (const uint4*)lds;
    uint4* o4 = (uint4*)out;
    for (int i = t; i < n4; i += 512) o4[i] = l4[i];
}

// merge S u4 partial copies -> bf16 A row (pad cols zero) + reciprocal in-degree
__global__ __launch_bounds__(256) void k_abfrc(const uint* __restrict__ P8, int S,
        u16* __restrict__ Abf, float* __restrict__ rcnt) {
    int row = blockIdx.x;            // 0..3*NN-1
    int g = row / NN, m = row % NN;
    int t = threadIdx.x, w = t >> 6;
    float partial = 0.0f;
    if (t < P8W) {
        uint cnt[8] = {0, 0, 0, 0, 0, 0, 0, 0};
        for (int p = 0; p < S; ++p) {
            uint v = P8[(((size_t)p * 3 + g) * NN + m) * P8W + t];
#pragma unroll
            for (int k = 0; k < 8; ++k) cnt[k] += (v >> (4 * k)) & 15u;
        }
        uint4 o;
        o.x = (uint)f2b((float)cnt[0]) | ((uint)f2b((float)cnt[1]) << 16);
        o.y = (uint)f2b((float)cnt[2]) | ((uint)f2b((float)cnt[3]) << 16);
        o.z = (uint)f2b((float)cnt[4]) | ((uint)f2b((float)cnt[5]) << 16);
        o.w = (uint)f2b((float)cnt[6]) | ((uint)f2b((float)cnt[7]) << 16);
        *(uint4*)(Abf + (size_t)row * NPAD + t * 8) = o;
#pragma unroll
        for (int k = 0; k < 8; ++k) partial += (float)cnt[k];
    }
    partial = wsum(partial);
    __shared__ float ws4[4];
    if ((t & 63) == 0) ws4[w] = partial;
    __syncthreads();
    if (t == 0)
        rcnt[g * NPAD + m] = 1.0f / fmaxf(ws4[0] + ws4[1] + ws4[2] + ws4[3], 1.0f);
}

// MFMA transform: Hout[d][col] = sum_k W[d][k]*x[col][k] (+bias[d]), transposed
// bf16 hi/lo output planes. A=W (hi/lo), B=x rows (hi/lo), hh+hl+lh products.
// Used for: L1 (x=embF), L2 (x=h1agg[g]), cuWT (x=cu, bias=null).
__global__ __launch_bounds__(256) void k_xf2(const float* __restrict__ xsrc,
        size_t xgstride, int ngb, int rowlim,
        const float* __restrict__ W, const float* __restrict__ bias,
        u16* __restrict__ Hhi, u16* __restrict__ Hlo, size_t hgstride, int ostride) {
    int b = blockIdx.x;
    int g = b / ngb, nt = b % ngb;
    int n0 = nt * 64;
    int t = threadIdx.x, w = t >> 6, l = t & 63;
    __shared__ u16 Ah[64 * LSTR], Al[64 * LSTR], Bh[64 * LSTR], Bl[64 * LSTR];
    __shared__ float bs[64];
    if (t < 64) bs[t] = bias ? bias[t] : 0.0f;
    // stage: thread t -> row r = t>>2 (0..63), col-segment c0 = (t&3)*16
    int r = t >> 2, c0 = (t & 3) * 16;
    {
        const float* Wr = W + r * 64 + c0;
        int node = n0 + r;
        const float* Xr = xsrc + xgstride * g + (size_t)node * 64 + c0;
        bool xv = node < rowlim;
#pragma unroll
        for (int j = 0; j < 4; ++j) {
            float4 wv = *(const float4*)(Wr + j * 4);
            float4 xw = xv ? *(const float4*)(Xr + j * 4) : (float4){0.f, 0.f, 0.f, 0.f};
            float a4[4] = {wv.x, wv.y, wv.z, wv.w};
            float b4[4] = {xw.x, xw.y, xw.z, xw.w};
            u16 ah[4], al[4], bh[4], bl[4];
#pragma unroll
            for (int jj = 0; jj < 4; ++jj) {
                ah[jj] = f2b(a4[jj]); al[jj] = f2b(a4[jj] - b2f16(ah[jj]));
                bh[jj] = f2b(b4[jj]); bl[jj] = f2b(b4[jj] - b2f16(bh[jj]));
            }
            uint2 pa, pb, pc, pd;
            pa.x = (uint)ah[0] | ((uint)ah[1] << 16); pa.y = (uint)ah[2] | ((uint)ah[3] << 16);
            pb.x = (uint)al[0] | ((uint)al[1] << 16); pb.y = (uint)al[2] | ((uint)al[3] << 16);
            pc.x = (uint)bh[0] | ((uint)bh[1] << 16); pc.y = (uint)bh[2] | ((uint)bh[3] << 16);
            pd.x = (uint)bl[0] | ((uint)bl[1] << 16); pd.y = (uint)bl[2] | ((uint)bl[3] << 16);
            int off = r * LSTR + c0 + j * 4;
            *(uint2*)(Ah + off) = pa;
            *(uint2*)(Al + off) = pb;
            *(uint2*)(Bh + off) = pc;
            *(uint2*)(Bl + off) = pd;
        }
    }
    __syncthreads();
    f32x4 acc[4];
#pragma unroll
    for (int p = 0; p < 4; ++p) acc[p] = (f32x4){0.f, 0.f, 0.f, 0.f};
    int mrow = w * 16 + (l & 15);
    int q8 = (l >> 4) * 8;
#pragma unroll
    for (int ks = 0; ks < 2; ++ks) {
        short8 ah = *(const short8*)(Ah + mrow * LSTR + ks * 32 + q8);
        short8 al = *(const short8*)(Al + mrow * LSTR + ks * 32 + q8);
#pragma unroll
        for (int p = 0; p < 4; ++p) {
            int nrow = p * 16 + (l & 15);
            short8 bh = *(const short8*)(Bh + nrow * LSTR + ks * 32 + q8);
            short8 bl = *(const short8*)(Bl + nrow * LSTR + ks * 32 + q8);
            acc[p] = __builtin_amdgcn_mfma_f32_16x16x32_bf16(ah, bh, acc[p], 0, 0, 0);
            acc[p] = __builtin_amdgcn_mfma_f32_16x16x32_bf16(ah, bl, acc[p], 0, 0, 0);
            acc[p] = __builtin_amdgcn_mfma_f32_16x16x32_bf16(al, bh, acc[p], 0, 0, 0);
        }
    }
    int q = l >> 4;
#pragma unroll
    for (int p = 0; p < 4; ++p) {
        int node = n0 + p * 16 + (l & 15);
#pragma unroll
        for (int rr2 = 0; rr2 < 4; ++rr2) {
            int d = w * 16 + q * 4 + rr2;
            float v = acc[p][rr2] + bs[d];
            u16 h = f2b(v);
            size_t o = hgstride * g + (size_t)d * ostride + node;
            Hhi[o] = h;
            Hlo[o] = f2b(v - b2f16(h));
        }
    }
}

// MFMA aggregation with split-bf16 B; K-split partials
__global__ __launch_bounds__(256) void k_aggp(const u16* __restrict__ Abf,
        const u16* __restrict__ Hhi, const u16* __restrict__ Hlo, size_t hstride,
        float* __restrict__ part) {
    int b = blockIdx.x;
    int kt = b & 7;
    int mt = (b >> 3) % MT;
    int g  = (b >> 3) / MT;
    int t = threadIdx.x, w = t >> 6, l = t & 63;
    __shared__ u16 As[64 * LSTR], Bh[64 * LSTR], Bl[64 * LSTR];
    f32x4 acc[4];
#pragma unroll
    for (int p = 0; p < 4; ++p) acc[p] = (f32x4){0.f, 0.f, 0.f, 0.f};
    int m0 = mt * 64;
    const u16* Ag = Abf + (size_t)g * NN * NPAD;
    const u16* Hg = Hhi + hstride * g;
    const u16* Lg = Hlo + hstride * g;
    int st0 = kt * CHUNK;
    int st1 = st0 + CHUNK; if (st1 > MT) st1 = MT;
    int rr = t >> 4, c4 = (t & 15) * 4;
    for (int st = st0; st < st1; ++st) {
        int s0 = st * 64;
        __syncthreads();
#pragma unroll
        for (int pass = 0; pass < 4; ++pass) {
            int r = pass * 16 + rr;
            uint2 av = {0u, 0u};
            if (m0 + r < NN) av = *(const uint2*)(Ag + (size_t)(m0 + r) * NPAD + s0 + c4);
            *(uint2*)(As + r * LSTR + c4) = av;
            *(uint2*)(Bh + r * LSTR + c4) = *(const uint2*)(Hg + (size_t)r * NPAD + s0 + c4);
            *(uint2*)(Bl + r * LSTR + c4) = *(const uint2*)(Lg + (size_t)r * NPAD + s0 + c4);
        }
        __syncthreads();
        int mrow = w * 16 + (l & 15);
        int q8 = (l >> 4) * 8;
#pragma unroll
        for (int ks = 0; ks < 2; ++ks) {
            short8 a = *(const short8*)(As + mrow * LSTR + ks * 32 + q8);
#pragma unroll
            for (int p = 0; p < 4; ++p) {
                int nrow = p * 16 + (l & 15);
                short8 bh = *(const short8*)(Bh + nrow * LSTR + ks * 32 + q8);
                short8 bl = *(const short8*)(Bl + nrow * LSTR + ks * 32 + q8);
                acc[p] = __builtin_amdgcn_mfma_f32_16x16x32_bf16(a, bh, acc[p], 0, 0, 0);
                acc[p] = __builtin_amdgcn_mfma_f32_16x16x32_bf16(a, bl, acc[p], 0, 0, 0);
            }
        }
    }
    int q = l >> 4;
#pragma unroll
    for (int p = 0; p < 4; ++p) {
        int n = p * 16 + (l & 15);
#pragma unroll
        for (int r = 0; r < 4; ++r) {
            int m = m0 + w * 16 + q * 4 + r;
            if (m < NN)
                part[(((size_t)kt * 3 + g) * NPAD + m) * 64 + n] = acc[p][r];
        }
    }
}

// layer-1 combine: h1agg = tanh(sum_kt part * rcnt), fp32
__global__ __launch_bounds__(256) void k_comb1(const float* __restrict__ part,
        const float* __restrict__ rcnt, float* __restrict__ h1) {
    int g = blockIdx.x / CPG, bi = blockIdx.x % CPG;
    int idx = bi * 256 + threadIdx.x;
    if (idx >= NN * 64) return;
    int m = idx >> 6;
    float s = 0.0f;
#pragma unroll
    for (int k = 0; k < KT; ++k)
        s += part[(((size_t)k * 3 + g) * NPAD + m) * 64 + (idx & 63)];
    h1[(size_t)g * NN * 64 + idx] = tanhf(s * rcnt[g * NPAD + m]);
}

// layer-2 combine + views-1..3 user column sumsq accumulation
__global__ __launch_bounds__(256) void k_comb(const float* __restrict__ part,
        const float* __restrict__ rcnt, float* __restrict__ out, float* __restrict__ cnss) {
    int g = blockIdx.x / CPG, bi = blockIdx.x % CPG;
    int t = threadIdx.x;
    int idx = bi * 256 + t;                 // within graph
    int m = idx >> 6, n = idx & 63;
    bool valid = idx < NN * 64;
    float v = 0.0f;
    if (valid) {
        float s = 0.0f;
#pragma unroll
        for (int k = 0; k < KT; ++k)
            s += part[(((size_t)k * 3 + g) * NPAD + m) * 64 + n];
        v = tanhf(s * rcnt[g * NPAD + m]);
        out[(size_t)g * NN * 64 + idx] = v;
    }
    float x2 = (valid && m < NUSER) ? v * v : 0.0f;
    __shared__ float sd[256];
    sd[t] = x2;
    __syncthreads();
    if (t < 64) {
        float s = sd[t] + sd[t + 64] + sd[t + 128] + sd[t + 192];
        if (s != 0.0f) atomicAdd(&cnss[(g + 1) * 64 + t], s);
    }
}

// cu (item rows, 4-view row-norm fusion) + ci (user rows, 4-view col-norm fusion)
__global__ void k_cuci(const float* __restrict__ embf, const float* __restrict__ out2,
                       const float* __restrict__ cnss, float* __restrict__ cu,
                       float* __restrict__ ci) {
    int b = blockIdx.x, l = threadIdx.x;
    if (b < 448) {
        if (b >= NITEM) { cu[(size_t)b * DD + l] = 0.0f; return; }
        int node = NUSER + b;
        const float* v0 = embf + (size_t)node * DD;
        const float* v1 = out2 + (size_t)node * DD;
        const float* v2 = out2 + OUT2STRIDE + (size_t)node * DD;
        const float* v3 = out2 + 2ull * OUT2STRIDE + (size_t)node * DD;
        float total = 0.0f;
        { float x = v0[l]; float ss = wsum(x * x); total += x / sqrtf(ss); }
        { float x = v1[l]; float ss = wsum(x * x); total += x / sqrtf(ss); }
        { float x = v2[l]; float ss = wsum(x * x); total += x / sqrtf(ss); }
        { float x = v3[l]; float ss = wsum(x * x); total += x / sqrtf(ss); }
        cu[(size_t)b * DD + l] = 0.25f * total;
    } else {
        int u = b - 448;
        size_t i = (size_t)u * DD + l;
        float s = embf[i] / sqrtf(cnss[l])
                + out2[i] / sqrtf(cnss[64 + l])
                + out2[OUT2STRIDE + i] / sqrtf(cnss[128 + l])
                + out2[2ull * OUT2STRIDE + i] / sqrtf(cnss[192 + l]);
        ci[i] = 0.25f * s;
    }
}

// h_pre = (presc @ cuWT^T)/rowsum + bias via MFMA; rowsum from ones-column MFMA;
// + BN partial sums. Fragment layout identical to k_aggp.
__global__ __launch_bounds__(256) void k_esynd(const void* __restrict__ presc,
        const u16* __restrict__ cwh, const u16* __restrict__ cwl,
        const float* __restrict__ mlpB, const int* __restrict__ flag,
        float* __restrict__ hpre, float* __restrict__ bnsum) {
    int m0 = blockIdx.x * 64;
    int t = threadIdx.x, w = t >> 6, l = t & 63;
    int isbf = *flag;
    const u16* pB = (const u16*)presc;
    const float* pF = (const float*)presc;
    __shared__ u16 As[64 * LSTR], Bh[64 * LSTR], Bl[64 * LSTR];
    __shared__ u16 Ones[16 * LSTR];
    __shared__ float bs[64];
    __shared__ float r1[4][64], r2[4][64];
    for (int i = t; i < 16 * LSTR; i += 256) Ones[i] = (i < 64) ? 0x3F80u : 0u;
    if (t < 64) bs[t] = mlpB[t];

    f32x4 acc[4], acc1;
#pragma unroll
    for (int p = 0; p < 4; ++p) acc[p] = (f32x4){0.f, 0.f, 0.f, 0.f};
    acc1 = (f32x4){0.f, 0.f, 0.f, 0.f};

    int rr = t >> 4, c4 = (t & 15) * 4;
    for (int st = 0; st < ENT; ++st) {
        int s0 = st * 64;
        __syncthreads();
#pragma unroll
        for (int pass = 0; pass < 4; ++pass) {
            int r = pass * 16 + rr;
            int m = m0 + r;
            int kb = s0 + c4;
            u16 a4[4];
            if (kb + 3 < NITEM) {
                if (isbf) {
                    const uint* p32 = (const uint*)pB + (((size_t)m * NITEM + kb) >> 1);
                    uint u0 = p32[0], u1 = p32[1];
                    a4[0] = (u16)u0; a4[1] = (u16)(u0 >> 16);
                    a4[2] = (u16)u1; a4[3] = (u16)(u1 >> 16);
                } else {
                    const float2* pf2 = (const float2*)(pF + (size_t)m * NITEM + kb);
                    float2 f0 = pf2[0], f1 = pf2[1];
                    a4[0] = f2b(f0.x); a4[1] = f2b(f0.y);
                    a4[2] = f2b(f1.x); a4[3] = f2b(f1.y);
                }
            } else {
#pragma unroll
                for (int j = 0; j < 4; ++j) {
                    int k = kb + j;
                    a4[j] = (k < NITEM)
                          ? (isbf ? pB[(size_t)m * NITEM + k] : f2b(pF[(size_t)m * NITEM + k]))
                          : (u16)0;
                }
            }
            uint2 o;
            o.x = (uint)a4[0] | ((uint)a4[1] << 16);
            o.y = (uint)a4[2] | ((uint)a4[3] << 16);
            *(uint2*)(As + r * LSTR + c4) = o;
            *(uint2*)(Bh + r * LSTR + c4) = *(const uint2*)(cwh + (size_t)r * KPAD + s0 + c4);
            *(uint2*)(Bl + r * LSTR + c4) = *(const uint2*)(cwl + (size_t)r * KPAD + s0 + c4);
        }
        __syncthreads();
        int mrow = w * 16 + (l & 15);
        int q8 = (l >> 4) * 8;
#pragma unroll
        for (int ks = 0; ks < 2; ++ks) {
            short8 a = *(const short8*)(As + mrow * LSTR + ks * 32 + q8);
            short8 on = *(const short8*)(Ones + (l & 15) * LSTR + ks * 32 + q8);
            acc1 = __builtin_amdgcn_mfma_f32_16x16x32_bf16(a, on, acc1, 0, 0, 0);
#pragma unroll
            for (int p = 0; p < 4; ++p) {
                int nrow = p * 16 + (l & 15);
                short8 bh = *(const short8*)(Bh + nrow * LSTR + ks * 32 + q8);
                short8 bl = *(const short8*)(Bl + nrow * LSTR + ks * 32 + q8);
                acc[p] = __builtin_amdgcn_mfma_f32_16x16x32_bf16(a, bh, acc[p], 0, 0, 0);
                acc[p] = __builtin_amdgcn_mfma_f32_16x16x32_bf16(a, bl, acc[p], 0, 0, 0);
            }
        }
    }
    float inv[4];
#pragma unroll
    for (int r = 0; r < 4; ++r)
        inv[r] = 1.0f / __shfl(acc1[r], l & 48, 64);
    int q = l >> 4;
#pragma unroll
    for (int p = 0; p < 4; ++p) {
        int col = p * 16 + (l & 15);
        float a = 0.0f, c = 0.0f;
#pragma unroll
        for (int r = 0; r < 4; ++r) {
            float hv = acc[p][r] * inv[r] + bs[col];
            hpre[(size_t)(m0 + w * 16 + q * 4 + r) * DD + col] = hv;
            a += hv; c = fmaf(hv, hv, c);
        }
        a += __shfl_xor(a, 16, 64); a += __shfl_xor(a, 32, 64);
        c += __shfl_xor(c, 16, 64); c += __shfl_xor(c, 32, 64);
        if (l < 16) { r1[w][col] = a; r2[w][col] = c; }
    }
    __syncthreads();
    if (t < 64) {
        atomicAdd(&bnsum[t],      r1[0][t] + r1[1][t] + r1[2][t] + r1[3][t]);
        atomicAdd(&bnsum[64 + t], r2[0][t] + r2[1][t] + r2[2][t] + r2[3][t]);
    }
}

// pre = relu(BN(h_pre)) @ ci^T via MFMA 64x64 tiles, bf16 hi/lo both operands.
__global__ __launch_bounds__(256) void k_final(const float* __restrict__ hpre,
        const float* __restrict__ bnsum, const float* __restrict__ gamma,
        const float* __restrict__ beta, const float* __restrict__ ci,
        void* __restrict__ out, const int* __restrict__ flag) {
    int b = blockIdx.x;
    int mt = b / FNT, nt = b % FNT;
    int m0 = mt * 64, n0 = nt * 64;
    int t = threadIdx.x, w = t >> 6, l = t & 63;
    __shared__ u16 Ah[64 * LSTR], Al[64 * LSTR], Bh[64 * LSTR], Bl[64 * LSTR];
    __shared__ float mn[64], rsg[64], bt[64];
    if (t < 64) {
        float mean = bnsum[t] * (1.0f / BB);
        float var = bnsum[64 + t] * (1.0f / BB) - mean * mean;
        mn[t] = mean;
        rsg[t] = gamma[t] / sqrtf(var + 1e-5f);
        bt[t] = beta[t];
    }
    __syncthreads();
    const float4* hp4 = (const float4*)(hpre + (size_t)m0 * 64);
    const float4* ci4 = (const float4*)ci;
#pragma unroll
    for (int k = 0; k < 4; ++k) {
        int i = t + k * 256;
        int r = i >> 4, c4 = (i & 15) * 4;
        float4 v = hp4[i];
        float vv[4] = {v.x, v.y, v.z, v.w};
        u16 hh[4], ll[4];
#pragma unroll
        for (int j = 0; j < 4; ++j) {
            int d = c4 + j;
            float x = fmaxf((vv[j] - mn[d]) * rsg[d] + bt[d], 0.0f);
            u16 hb = f2b(x);
            hh[j] = hb;
            ll[j] = f2b(x - b2f16(hb));
        }
        uint2 ph, pl;
        ph.x = (uint)hh[0] | ((uint)hh[1] << 16);
        ph.y = (uint)hh[2] | ((uint)hh[3] << 16);
        pl.x = (uint)ll[0] | ((uint)ll[1] << 16);
        pl.y = (uint)ll[2] | ((uint)ll[3] << 16);
        *(uint2*)(Ah + r * LSTR + c4) = ph;
        *(uint2*)(Al + r * LSTR + c4) = pl;
        int col = n0 + r;
        float4 cv = (col < NUSER) ? ci4[(size_t)col * 16 + (i & 15)]
                                  : (float4){0.f, 0.f, 0.f, 0.f};
        float cc[4] = {cv.x, cv.y, cv.z, cv.w};
#pragma unroll
        for (int j = 0; j < 4; ++j) {
            u16 hb = f2b(cc[j]);
            hh[j] = hb;
            ll[j] = f2b(cc[j] - b2f16(hb));
        }
        ph.x = (uint)hh[0] | ((uint)hh[1] << 16);
        ph.y = (uint)hh[2] | ((uint)hh[3] << 16);
        pl.x = (uint)ll[0] | ((uint)ll[1] << 16);
        pl.y = (uint)ll[2] | ((uint)ll[3] << 16);
        *(uint2*)(Bh + r * LSTR + c4) = ph;
        *(uint2*)(Bl + r * LSTR + c4) = pl;
    }
    __syncthreads();
    f32x4 acc[4];
#pragma unroll
    for (int p = 0; p < 4; ++p) acc[p] = (f32x4){0.f, 0.f, 0.f, 0.f};
    int mrow = w * 16 + (l & 15);
    int q8 = (l >> 4) * 8;
#pragma unroll
    for (int ks = 0; ks < 2; ++ks) {
        short8 ah = *(const short8*)(Ah + mrow * LSTR + ks * 32 + q8);
        short8 al = *(const short8*)(Al + mrow * LSTR + ks * 32 + q8);
#pragma unroll
        for (int p = 0; p < 4; ++p) {
            int nrow = p * 16 + (l & 15);
            short8 bh = *(const short8*)(Bh + nrow * LSTR + ks * 32 + q8);
            short8 bl = *(const short8*)(Bl + nrow * LSTR + ks * 32 + q8);
            acc[p] = __builtin_amdgcn_mfma_f32_16x16x32_bf16(ah, bh, acc[p], 0, 0, 0);
            acc[p] = __builtin_amdgcn_mfma_f32_16x16x32_bf16(ah, bl, acc[p], 0, 0, 0);
            acc[p] = __builtin_amdgcn_mfma_f32_16x16x32_bf16(al, bh, acc[p], 0, 0, 0);
        }
    }
    int isbf = *flag;
    int q = l >> 4;
#pragma unroll
    for (int p = 0; p < 4; ++p) {
        int col = n0 + p * 16 + (l & 15);
        if (col < NUSER) {
#pragma unroll
            for (int r = 0; r < 4; ++r) {
                int row = m0 + w * 16 + q * 4 + r;
                size_t o = (size_t)row * NUSER + col;
                if (isbf) ((__hip_bfloat16*)out)[o] = __float2bfloat16(acc[p][r]);
                else      ((float*)out)[o] = acc[p][r];
            }
        }
    }
}

extern "C" void kernel_launch(void* const* d_in, const int* in_sizes, int n_in,
                              void* d_out, int out_size, void* d_ws, size_t ws_size,
                              hipStream_t stream) {
    const void* presc = d_in[1];
    const void* emb   = d_in[2];
    const void* W1    = d_in[3];
    const void* b1    = d_in[4];
    const void* W2    = d_in[5];
    const void* b2    = d_in[6];
    const void* mlpW  = d_in[7];
    const void* mlpB  = d_in[8];
    const void* gamma = d_in[9];
    const void* beta  = d_in[10];
    const int* tg = (const int*)d_in[11];
    const int* s1 = (const int*)d_in[12];
    const int* s2 = (const int*)d_in[13];
    float* ws = (float*)d_ws;
    (void)in_sizes; (void)n_in; (void)out_size;

    float* bnsum = ws + OFF_BNS;
    float* cnss  = ws + OFF_CNSS;
    int*   flag  = (int*)(ws + OFF_FLAG);
    float* cvt   = ws + OFF_CVT;
    float* embF  = cvt + CVT_EMB;
    float* W1F   = cvt + CVT_W1;
    float* b1F   = cvt + CVT_B1;
    float* W2F   = cvt + CVT_W2;
    float* b2F   = cvt + CVT_B2;
    float* mlpWF = cvt + CVT_MLPW;
    float* mlpBF = cvt + CVT_MLPB;
    float* gamF  = cvt + CVT_GAMMA;
    float* betF  = cvt + CVT_BETA;
    u16*   Abf   = (u16*)(ws + OFF_ABF);
    float* rcnt  = ws + OFF_RC;
    uint*  P8    = (uint*)(ws + OFF_POOL);
    float* part  = ws + OFF_PART;
    u16*   H1hi  = (u16*)(ws + OFF_H1);
    u16*   H1lo  = H1hi + 64ull * NPAD;
    u16*   H2hi  = (u16*)(ws + OFF_H2);
    u16*   H2lo  = H2hi + 3ull * 64 * NPAD;
    float* out2  = ws + OFF_OUT2;          // h1agg lives here first, then out2
    float* cu    = ws + OFF_CU;
    float* ci    = ws + OFF_CI;
    float* hpre  = ws + OFF_H;
    // cuWT hi/lo alias the dead part buffer
    u16*   cwh   = (u16*)(ws + OFF_PART);
    u16*   cwl   = cwh + 64ull * KPAD;

    size_t p8per = 3ull * NN * P8W;        // floats (==u32) per partial copy
    int S = 4;
    if      (ws_size >= (OFF_POOL + 16ull * p8per) * 4) S = 16;
    else if (ws_size >= (OFF_POOL +  8ull * p8per) * 4) S = 8;

    hipMemsetAsync(ws, 0, MEMSET_FLOATS * sizeof(float), stream);   // bnsum + cnss
    k_cvt_all<<<CVT_TOTAL / 256, 256, 0, stream>>>(
        presc, emb, W1, b1, W2, b2, mlpW, mlpB, gamma, beta, cvt, cnss, flag);

    k_histp<<<3 * RB * S, 512, 0, stream>>>(tg, s1, s2, P8, S);
    k_abfrc<<<3 * NN, 256, 0, stream>>>(P8, S, Abf, rcnt);

    // layer 1: H1 = emb@W1^T+b1 (graph-independent), agg, combine to fp32
    k_xf2<<<MT, 256, 0, stream>>>(embF, 0, MT, NN, W1F, b1F, H1hi, H1lo, 0, NPAD);
    k_aggp<<<3 * MT * KT, 256, 0, stream>>>(Abf, H1hi, H1lo, 0, part);
    k_comb1<<<3 * CPG, 256, 0, stream>>>(part, rcnt, out2);   // h1agg
    // layer 2
    k_xf2<<<3 * MT, 256, 0, stream>>>(out2, (size_t)NN * 64, MT, NN, W2F, b2F,
                                      H2hi, H2lo, 64ull * NPAD, NPAD);
    k_aggp<<<3 * MT * KT, 256, 0, stream>>>(Abf, H2hi, H2lo, 64ull * NPAD, part);
    k_comb<<<3 * CPG, 256, 0, stream>>>(part, rcnt, out2, cnss);

    // view fusion + cuWT = cu @ mlpW^T (bias-free k_xf2)
    k_cuci<<<448 + NUSER, 64, 0, stream>>>(embF, out2, cnss, cu, ci);
    k_xf2<<<ENT, 256, 0, stream>>>(cu, 0, ENT, 448, mlpWF, nullptr, cwh, cwl, 0, KPAD);

    // pooling+MLP GEMM (+BN partials) + final GEMM
    k_esynd<<<BB / 64, 256, 0, stream>>>(presc, cwh, cwl, mlpBF, flag, hpre, bnsum);
    k_final<<<(BB / 64) * FNT, 256, 0, stream>>>(hpre, bnsum, gamF, betF, ci, d_out, flag);
}